// Round 9
// baseline (76871.857 us; speedup 1.0000x reference)
//
#include <hip/hip_runtime.h>

// ---- problem constants ----
constexpr int SQ = 8192;   // sequence length
constexpr int HD = 256;    // hidden size H
constexpr int NG = 1024;   // 4H (gate width)

typedef __fp16 h2 __attribute__((ext_vector_type(2)));
typedef unsigned int uint;
typedef unsigned short ushort;

__device__ __forceinline__ float sigm_f(float x) {
  float e = __builtin_amdgcn_exp2f(-1.4426950408889634f * x);
  return __builtin_amdgcn_rcpf(1.0f + e);
}
__device__ __forceinline__ float tanh_f(float x) {
  float e = __builtin_amdgcn_exp2f(2.885390081777927f * x);
  return 1.0f - 2.0f * __builtin_amdgcn_rcpf(1.0f + e);
}
__device__ __forceinline__ h2 bch2(uint v) { return __builtin_bit_cast(h2, v); }
__device__ __forceinline__ uint pk(float a, float b) {
  return __builtin_bit_cast(uint, __builtin_amdgcn_cvt_pkrtz(a, b));
}
// xor lane-bit-0 exchange via DPP quad_perm [1,0,3,2] — pure VALU, no DS pipe
__device__ __forceinline__ float dpp_xor1(float x) {
  int v = __builtin_amdgcn_mov_dpp(__builtin_bit_cast(int, x), 0xB1, 0xF, 0xF, true);
  return __builtin_bit_cast(float, v);
}

// =====================================================================
// xp GEMM: out[d][m][n] = sum_k A[m][k] * W[d][k][n] + bias[d][n]
// =====================================================================
__global__ __launch_bounds__(256) void gemm_xp(const float* __restrict__ A, int K,
                                               const float* __restrict__ W,
                                               const float* __restrict__ bias,
                                               float* __restrict__ out) {
  __shared__ float Al[16][64];  // [k][m]
  __shared__ float Bl[16][64];  // [k][n]
  const int tid = threadIdx.x;
  const int bm = blockIdx.x * 64;
  const int d  = blockIdx.y >> 4;
  const int bn = (blockIdx.y & 15) * 64;
  const float* Wd = W + (size_t)d * K * NG;
  const float* bd = bias + (size_t)d * NG;
  float* outd = out + (size_t)d * SQ * NG;

  const int m4 = (tid >> 4) << 2;
  const int n4 = (tid & 15) << 2;
  const int am = tid >> 2, ak = (tid & 3) << 2;
  const int bk = tid >> 4, bnn = (tid & 15) << 2;

  float acc[4][4] = {};
  for (int kt = 0; kt < K; kt += 16) {
    float4 av = *(const float4*)(A + (size_t)(bm + am) * K + kt + ak);
    float4 bv = *(const float4*)(Wd + (size_t)(kt + bk) * NG + bn + bnn);
    __syncthreads();
    Al[ak + 0][am] = av.x;
    Al[ak + 1][am] = av.y;
    Al[ak + 2][am] = av.z;
    Al[ak + 3][am] = av.w;
    *(float4*)&Bl[bk][bnn] = bv;
    __syncthreads();
#pragma unroll
    for (int k = 0; k < 16; ++k) {
      float4 a = *(const float4*)&Al[k][m4];
      float4 b = *(const float4*)&Bl[k][n4];
      float ar[4] = {a.x, a.y, a.z, a.w};
      float br[4] = {b.x, b.y, b.z, b.w};
#pragma unroll
      for (int i = 0; i < 4; ++i)
#pragma unroll
        for (int jj = 0; jj < 4; ++jj)
          acc[i][jj] = fmaf(ar[i], br[jj], acc[i][jj]);
    }
  }
#pragma unroll
  for (int i = 0; i < 4; ++i) {
    float4 o;
    o.x = acc[i][0] + bd[bn + n4 + 0];
    o.y = acc[i][1] + bd[bn + n4 + 1];
    o.z = acc[i][2] + bd[bn + n4 + 2];
    o.w = acc[i][3] + bd[bn + n4 + 3];
    *(float4*)(outd + (size_t)(bm + m4 + i) * NG + bn + n4) = o;
  }
}

// =====================================================================
// LSTM recurrence v10 = v9 with conflict-free LDS layouts.
// 1 workgroup/direction, 512 threads (8 waves). Thread j: unit u=j>>1,
// K-half s=j&1; owns all 4 gate columns of unit u over rows
// [s*128, s*128+128): 224 weight regs + 2 LDS quads per gate.
//   wlq flat layout [g][q][u][s]: flat idx = (g*2+q)*512 + j
//     -> each wave reads 1024 consecutive bytes: ZERO bank conflicts
//        (v9's [s][g][q][u] was ~4-way conflicted).
//   hl halves padded to 72-dword stride: the two broadcast address sets
//     start 8 banks apart (v9's +256B aliased to the same banks).
// Per step: 16 h-quad broadcasts, 256 fdot2, DPP-xor1 K-combine,
// redundant pair-lane update, one raw lgkmcnt-only s_barrier.
// LDS pad keeps 1 block/CU.
// =====================================================================
__global__ __launch_bounds__(512, 1) void lstm_rec10(const float* __restrict__ Whh,
                                                     const float* __restrict__ xp,
                                                     float* __restrict__ obuf) {
  __shared__ uint4 wlq[4096];       // 64KB, flat [g][q][u][s]
  __shared__ uint  hl[2][144];      // [parity][dword], half s at s*72
  __shared__ uint  pad_[8192];      // 32KB occupancy pad -> 1 block/CU
  const int d = blockIdx.x;
  const int j = threadIdx.x;
  const int u = j >> 1;             // unit 0..255
  const int s = j & 1;              // K-half
  const float* W   = Whh + (size_t)d * HD * NG;
  const float* xpd = xp + (size_t)d * SQ * NG;

  // ---- fill LDS weights: rows [ss*128+112, ss*128+128) ----
  for (int idx = j; idx < 4096; idx += 512) {
    const int ss = idx & 1;
    const int uu = (idx >> 1) & 255;
    const int q  = (idx >> 9) & 1;
    const int g  = idx >> 10;
    const int r0 = ss * 128 + 112 + q * 8;
    const int c  = g * 256 + uu;
    uint4 v;
    v.x = pk(W[(size_t)(r0 + 0) * NG + c], W[(size_t)(r0 + 1) * NG + c]);
    v.y = pk(W[(size_t)(r0 + 2) * NG + c], W[(size_t)(r0 + 3) * NG + c]);
    v.z = pk(W[(size_t)(r0 + 4) * NG + c], W[(size_t)(r0 + 5) * NG + c]);
    v.w = pk(W[(size_t)(r0 + 6) * NG + c], W[(size_t)(r0 + 7) * NG + c]);
    wlq[idx] = v;
  }
  if (j == 0) pad_[0] = 0u;   // keep pad alive

  // ---- register weights: rows [s*128, s*128+112) for 4 gate cols ----
  h2 wr[4][56];
#pragma unroll
  for (int g = 0; g < 4; ++g) {
    const float* Wc = W + (size_t)(s * 128) * NG + g * 256 + u;
#pragma unroll
    for (int k = 0; k < 56; ++k)
      wr[g][k] = __builtin_amdgcn_cvt_pkrtz(Wc[(size_t)(2 * k) * NG],
                                            Wc[(size_t)(2 * k + 1) * NG]);
  }

  if (j < 288) { ((uint*)hl)[j] = 0u; }
  __syncthreads();

  const int fwd = (d == 0) ? 1 : 0;
  int t = fwd ? 0 : SQ - 1;
  const int dt = fwd ? 1 : -1;
  float cc = 0.0f;
  int p = 0;

  float xc[4], xn[4] = {};
#pragma unroll
  for (int g = 0; g < 4; ++g) xc[g] = xpd[(size_t)t * NG + g * 256 + u];

  for (int step = 0; step < SQ; ++step) {
    // prefetch next xp (not drained by the raw barrier)
    if (step + 1 < SQ) {
#pragma unroll
      for (int g = 0; g < 4; ++g) xn[g] = xpd[(size_t)(t + dt) * NG + g * 256 + u];
    }

    // ---- dots over this thread's K-half ----
    const uint4* hb = (const uint4*)&hl[p][s * 72];   // 16 quads = 64 h2
    float acc[4] = {0.0f, 0.0f, 0.0f, 0.0f};
#pragma unroll
    for (int q = 0; q < 14; ++q) {          // register rows (0..111 of half)
      uint4 hq = hb[q];
      h2 hx = bch2(hq.x), hy = bch2(hq.y), hz = bch2(hq.z), hw = bch2(hq.w);
#pragma unroll
      for (int g = 0; g < 4; ++g) {
        acc[g] = __builtin_amdgcn_fdot2(wr[g][4 * q + 0], hx, acc[g], false);
        acc[g] = __builtin_amdgcn_fdot2(wr[g][4 * q + 1], hy, acc[g], false);
        acc[g] = __builtin_amdgcn_fdot2(wr[g][4 * q + 2], hz, acc[g], false);
        acc[g] = __builtin_amdgcn_fdot2(wr[g][4 * q + 3], hw, acc[g], false);
      }
    }
#pragma unroll
    for (int qq = 0; qq < 2; ++qq) {        // LDS rows (112..127 of half)
      uint4 hq = hb[14 + qq];
      h2 hx = bch2(hq.x), hy = bch2(hq.y), hz = bch2(hq.z), hw = bch2(hq.w);
#pragma unroll
      for (int g = 0; g < 4; ++g) {
        uint4 wq = wlq[(g * 2 + qq) * 512 + j];   // consecutive 16B per lane
        acc[g] = __builtin_amdgcn_fdot2(bch2(wq.x), hx, acc[g], false);
        acc[g] = __builtin_amdgcn_fdot2(bch2(wq.y), hy, acc[g], false);
        acc[g] = __builtin_amdgcn_fdot2(bch2(wq.z), hz, acc[g], false);
        acc[g] = __builtin_amdgcn_fdot2(bch2(wq.w), hw, acc[g], false);
      }
    }

    // ---- K-combine across the lane pair: pure-VALU DPP ----
#pragma unroll
    for (int g = 0; g < 4; ++g) acc[g] += dpp_xor1(acc[g]);

    // ---- redundant full update in both pair-lanes (identical FP) ----
    float iv = sigm_f(acc[0] + xc[0]);
    float fv = sigm_f(acc[1] + xc[1]);
    float gv = tanh_f(acc[2] + xc[2]);
    float ov = sigm_f(acc[3] + xc[3]);
    cc = fv * cc + iv * gv;
    float hv = ov * tanh_f(cc);

    if (s == 0) {
      obuf[(size_t)t * 512 + (d << 8) + u] = hv;     // fire-and-forget
      const int r  = u >> 1;                         // packed dword 0..127
      const int dw = r + ((r >> 6) << 3);            // +8 dwords pad for half 1
      ((ushort*)hl[p ^ 1])[dw * 2 + (u & 1)] = (ushort)(pk(hv, hv) & 0xFFFFu);
    }

    // ---- one raw barrier: LDS ordering only, no vmcnt drain ----
    asm volatile("s_waitcnt lgkmcnt(0)" ::: "memory");
    __builtin_amdgcn_s_barrier();
    __builtin_amdgcn_sched_barrier(0);

    p ^= 1;
#pragma unroll
    for (int g = 0; g < 4; ++g) xc[g] = xn[g];
    t += dt;
  }
}

// =====================================================================
// classifier head
// =====================================================================
__global__ void cls_k(const float* __restrict__ buf, const float* __restrict__ w1,
                      const float* __restrict__ b1, const float* __restrict__ w2,
                      const float* __restrict__ b2, float* __restrict__ out) {
  __shared__ float feat[512];
  __shared__ float hid[32];
  const int t = threadIdx.x;
  feat[t] = (t < 256) ? buf[(size_t)(SQ - 1) * 512 + t] : buf[t];
  __syncthreads();
  if (t < 32) {
    float a = b1[t];
    for (int k = 0; k < 512; ++k) a = fmaf(feat[k], w1[k * 32 + t], a);
    hid[t] = a;
  }
  __syncthreads();
  if (t < 2) {
    float a = b2[t];
    for (int k = 0; k < 32; ++k) a = fmaf(hid[k], w2[k * 2 + t], a);
    out[t] = a;
  }
}

// =====================================================================
extern "C" void kernel_launch(void* const* d_in, const int* in_sizes, int n_in,
                              void* d_out, int out_size, void* d_ws, size_t ws_size,
                              hipStream_t stream) {
  const float* x     = (const float*)d_in[0];
  const float* w_ih0 = (const float*)d_in[1];
  const float* w_hh0 = (const float*)d_in[2];
  const float* b0    = (const float*)d_in[3];
  const float* w_ih  = (const float*)d_in[4];
  const float* w_hh  = (const float*)d_in[5];
  const float* b     = (const float*)d_in[6];
  const float* w1    = (const float*)d_in[7];
  const float* b1    = (const float*)d_in[8];
  const float* w2    = (const float*)d_in[9];
  const float* b2    = (const float*)d_in[10];

  float* xp   = (float*)d_ws;                       // [2][SQ][NG] = 64MB
  float* bufA = xp + (size_t)2 * SQ * NG;           // [SQ][512]   = 16MB
  float* bufB = bufA + (size_t)SQ * 512;            // [SQ][512]   = 16MB

  const dim3 ggrid(SQ / 64, 32);

  // layer 0
  gemm_xp<<<ggrid, 256, 0, stream>>>(x, 1024, w_ih0, b0, xp);
  lstm_rec10<<<2, 512, 0, stream>>>(w_hh0, xp, bufA);

  // layers 1..4
  float* cur = bufA;
  float* nxt = bufB;
  for (int lyr = 0; lyr < 4; ++lyr) {
    gemm_xp<<<ggrid, 256, 0, stream>>>(cur, 512, w_ih + (size_t)lyr * 2 * 512 * 1024,
                                       b + (size_t)lyr * 2 * 1024, xp);
    lstm_rec10<<<2, 512, 0, stream>>>(w_hh + (size_t)lyr * 2 * 256 * 1024, xp, nxt);
    float* tmp = cur; cur = nxt; nxt = tmp;
  }

  cls_k<<<1, 512, 0, stream>>>(cur, w1, b1, w2, b2, (float*)d_out);
}

// Round 10
// 62864.423 us; speedup vs baseline: 1.2228x; 1.2228x over previous
//
#include <hip/hip_runtime.h>

// ---- problem constants ----
constexpr int SQ = 8192;   // sequence length
constexpr int HD = 256;    // hidden size H
constexpr int NG = 1024;   // 4H (gate width)

typedef __fp16 h2 __attribute__((ext_vector_type(2)));
typedef unsigned int uint;
typedef unsigned short ushort;

__device__ __forceinline__ float sigm_f(float x) {
  float e = __builtin_amdgcn_exp2f(-1.4426950408889634f * x);
  return __builtin_amdgcn_rcpf(1.0f + e);
}
__device__ __forceinline__ float tanh_f(float x) {
  float e = __builtin_amdgcn_exp2f(2.885390081777927f * x);
  return 1.0f - 2.0f * __builtin_amdgcn_rcpf(1.0f + e);
}
__device__ __forceinline__ h2 bch2(uint v) { return __builtin_bit_cast(h2, v); }
__device__ __forceinline__ uint pk(float a, float b) {
  return __builtin_bit_cast(uint, __builtin_amdgcn_cvt_pkrtz(a, b));
}
// xor lane-bit-0 exchange via DPP quad_perm [1,0,3,2] — pure VALU, no DS pipe
__device__ __forceinline__ float dpp_xor1(float x) {
  int v = __builtin_amdgcn_mov_dpp(__builtin_bit_cast(int, x), 0xB1, 0xF, 0xF, true);
  return __builtin_bit_cast(float, v);
}

// =====================================================================
// xp GEMM: out[d][m][n] = sum_k A[m][k] * W[d][k][n] + bias[d][n]
// =====================================================================
__global__ __launch_bounds__(256) void gemm_xp(const float* __restrict__ A, int K,
                                               const float* __restrict__ W,
                                               const float* __restrict__ bias,
                                               float* __restrict__ out) {
  __shared__ float Al[16][64];  // [k][m]
  __shared__ float Bl[16][64];  // [k][n]
  const int tid = threadIdx.x;
  const int bm = blockIdx.x * 64;
  const int d  = blockIdx.y >> 4;
  const int bn = (blockIdx.y & 15) * 64;
  const float* Wd = W + (size_t)d * K * NG;
  const float* bd = bias + (size_t)d * NG;
  float* outd = out + (size_t)d * SQ * NG;

  const int m4 = (tid >> 4) << 2;
  const int n4 = (tid & 15) << 2;
  const int am = tid >> 2, ak = (tid & 3) << 2;
  const int bk = tid >> 4, bnn = (tid & 15) << 2;

  float acc[4][4] = {};
  for (int kt = 0; kt < K; kt += 16) {
    float4 av = *(const float4*)(A + (size_t)(bm + am) * K + kt + ak);
    float4 bv = *(const float4*)(Wd + (size_t)(kt + bk) * NG + bn + bnn);
    __syncthreads();
    Al[ak + 0][am] = av.x;
    Al[ak + 1][am] = av.y;
    Al[ak + 2][am] = av.z;
    Al[ak + 3][am] = av.w;
    *(float4*)&Bl[bk][bnn] = bv;
    __syncthreads();
#pragma unroll
    for (int k = 0; k < 16; ++k) {
      float4 a = *(const float4*)&Al[k][m4];
      float4 b = *(const float4*)&Bl[k][n4];
      float ar[4] = {a.x, a.y, a.z, a.w};
      float br[4] = {b.x, b.y, b.z, b.w};
#pragma unroll
      for (int i = 0; i < 4; ++i)
#pragma unroll
        for (int jj = 0; jj < 4; ++jj)
          acc[i][jj] = fmaf(ar[i], br[jj], acc[i][jj]);
    }
  }
#pragma unroll
  for (int i = 0; i < 4; ++i) {
    float4 o;
    o.x = acc[i][0] + bd[bn + n4 + 0];
    o.y = acc[i][1] + bd[bn + n4 + 1];
    o.z = acc[i][2] + bd[bn + n4 + 2];
    o.w = acc[i][3] + bd[bn + n4 + 3];
    *(float4*)(outd + (size_t)(bm + m4 + i) * NG + bn + n4) = o;
  }
}

// =====================================================================
// LSTM recurrence v11 = v9 structure with the register budget fixed so
// ALL live state fits in architectural VGPRs (no AGPR copy tax).
// 512 threads (8 waves, 2/SIMD). Thread j: unit u=j>>1, K-half s=j&1;
// owns all 4 gate columns of unit u over rows [s*128, s*128+128):
//   rows [s*128, s*128+96):   48 h2 x 4 gates = 192 weight VGPRs
//   rows [s*128+96, s*128+128): LDS wl, flat [(g*4+qq)*512 + j]
//     -> each wave reads 1024 consecutive bytes per instr, conflict-free
// h buffer hl[2][128]: EXACT v9 layout (v10's re-layout regressed).
// Per step: 16 h-quad broadcasts, 192 reg-fdot2 + 64 LDS-fdot2,
// DPP-xor1 K-combine (pure VALU), redundant pair-lane tail,
// one raw lgkmcnt-only s_barrier (no vmcnt drain).
// LDS 129KB -> 1 block/CU naturally.
// =====================================================================
__global__ __launch_bounds__(512, 1) void lstm_rec11(const float* __restrict__ Whh,
                                                     const float* __restrict__ xp,
                                                     float* __restrict__ obuf) {
  __shared__ uint4 wl[16 * 512];   // 128KB: [(g*4+qq)][j], j = u*2+s
  __shared__ uint  hl[2][128];     // v9-exact: [parity][dword]
  const int d = blockIdx.x;
  const int j = threadIdx.x;
  const int u = j >> 1;            // unit 0..255
  const int s = j & 1;             // K-half
  const float* W   = Whh + (size_t)d * HD * NG;
  const float* xpd = xp + (size_t)d * SQ * NG;

  // ---- fill LDS weights: rows [ss*128+96, ss*128+128) ----
  for (int idx = j; idx < 16 * 512; idx += 512) {
    const int rem = idx & 511;
    const int uu  = rem >> 1;
    const int ss  = rem & 1;
    const int qq  = (idx >> 9) & 3;
    const int g   = idx >> 11;
    const int r0  = ss * 128 + 96 + 8 * qq;
    const int c   = g * 256 + uu;
    uint4 v;
    v.x = pk(W[(size_t)(r0 + 0) * NG + c], W[(size_t)(r0 + 1) * NG + c]);
    v.y = pk(W[(size_t)(r0 + 2) * NG + c], W[(size_t)(r0 + 3) * NG + c]);
    v.z = pk(W[(size_t)(r0 + 4) * NG + c], W[(size_t)(r0 + 5) * NG + c]);
    v.w = pk(W[(size_t)(r0 + 6) * NG + c], W[(size_t)(r0 + 7) * NG + c]);
    wl[idx] = v;
  }

  // ---- register weights: rows [s*128, s*128+96) for the 4 gate cols ----
  h2 wr[4][48];
#pragma unroll
  for (int g = 0; g < 4; ++g) {
    const float* Wc = W + (size_t)(s * 128) * NG + g * 256 + u;
#pragma unroll
    for (int k = 0; k < 48; ++k)
      wr[g][k] = __builtin_amdgcn_cvt_pkrtz(Wc[(size_t)(2 * k) * NG],
                                            Wc[(size_t)(2 * k + 1) * NG]);
  }

  if (j < 256) { ((uint*)hl)[j] = 0u; }
  __syncthreads();

  const int fwd = (d == 0) ? 1 : 0;
  int t = fwd ? 0 : SQ - 1;
  const int dt = fwd ? 1 : -1;
  float cc = 0.0f;
  int p = 0;

  float xc[4], xn[4] = {};
#pragma unroll
  for (int g = 0; g < 4; ++g) xc[g] = xpd[(size_t)t * NG + g * 256 + u];

  for (int step = 0; step < SQ; ++step) {
    // prefetch next xp (global; not drained by the raw barrier)
    if (step + 1 < SQ) {
#pragma unroll
      for (int g = 0; g < 4; ++g) xn[g] = xpd[(size_t)(t + dt) * NG + g * 256 + u];
    }

    // ---- dots over this thread's K-half ----
    const uint4* hb = (const uint4*)&hl[p][s * 64];   // 16 quads = 64 h2
    float acc[4] = {0.0f, 0.0f, 0.0f, 0.0f};
#pragma unroll
    for (int q = 0; q < 12; ++q) {          // register rows (0..95 of half)
      uint4 hq = hb[q];
      h2 hx = bch2(hq.x), hy = bch2(hq.y), hz = bch2(hq.z), hw = bch2(hq.w);
#pragma unroll
      for (int g = 0; g < 4; ++g) {
        acc[g] = __builtin_amdgcn_fdot2(wr[g][4 * q + 0], hx, acc[g], false);
        acc[g] = __builtin_amdgcn_fdot2(wr[g][4 * q + 1], hy, acc[g], false);
        acc[g] = __builtin_amdgcn_fdot2(wr[g][4 * q + 2], hz, acc[g], false);
        acc[g] = __builtin_amdgcn_fdot2(wr[g][4 * q + 3], hw, acc[g], false);
      }
    }
#pragma unroll
    for (int qq = 0; qq < 4; ++qq) {        // LDS rows (96..127 of half)
      uint4 hq = hb[12 + qq];
      h2 hx = bch2(hq.x), hy = bch2(hq.y), hz = bch2(hq.z), hw = bch2(hq.w);
#pragma unroll
      for (int g = 0; g < 4; ++g) {
        uint4 wq = wl[(g * 4 + qq) * 512 + j];   // consecutive 16B per lane
        acc[g] = __builtin_amdgcn_fdot2(bch2(wq.x), hx, acc[g], false);
        acc[g] = __builtin_amdgcn_fdot2(bch2(wq.y), hy, acc[g], false);
        acc[g] = __builtin_amdgcn_fdot2(bch2(wq.z), hz, acc[g], false);
        acc[g] = __builtin_amdgcn_fdot2(bch2(wq.w), hw, acc[g], false);
      }
    }

    // ---- K-combine across the lane pair: pure-VALU DPP ----
#pragma unroll
    for (int g = 0; g < 4; ++g) acc[g] += dpp_xor1(acc[g]);

    // ---- redundant full update in both pair-lanes (identical FP) ----
    float iv = sigm_f(acc[0] + xc[0]);
    float fv = sigm_f(acc[1] + xc[1]);
    float gv = tanh_f(acc[2] + xc[2]);
    float ov = sigm_f(acc[3] + xc[3]);
    cc = fv * cc + iv * gv;
    float hv = ov * tanh_f(cc);

    if (s == 0) {
      obuf[(size_t)t * 512 + (d << 8) + u] = hv;     // fire-and-forget
      ((ushort*)hl[p ^ 1])[u] = (ushort)(pk(hv, hv) & 0xFFFFu);
    }

    // ---- one raw barrier: LDS ordering only, no vmcnt drain ----
    asm volatile("s_waitcnt lgkmcnt(0)" ::: "memory");
    __builtin_amdgcn_s_barrier();
    __builtin_amdgcn_sched_barrier(0);

    p ^= 1;
#pragma unroll
    for (int g = 0; g < 4; ++g) xc[g] = xn[g];
    t += dt;
  }
}

// =====================================================================
// classifier head
// =====================================================================
__global__ void cls_k(const float* __restrict__ buf, const float* __restrict__ w1,
                      const float* __restrict__ b1, const float* __restrict__ w2,
                      const float* __restrict__ b2, float* __restrict__ out) {
  __shared__ float feat[512];
  __shared__ float hid[32];
  const int t = threadIdx.x;
  feat[t] = (t < 256) ? buf[(size_t)(SQ - 1) * 512 + t] : buf[t];
  __syncthreads();
  if (t < 32) {
    float a = b1[t];
    for (int k = 0; k < 512; ++k) a = fmaf(feat[k], w1[k * 32 + t], a);
    hid[t] = a;
  }
  __syncthreads();
  if (t < 2) {
    float a = b2[t];
    for (int k = 0; k < 32; ++k) a = fmaf(hid[k], w2[k * 2 + t], a);
    out[t] = a;
  }
}

// =====================================================================
extern "C" void kernel_launch(void* const* d_in, const int* in_sizes, int n_in,
                              void* d_out, int out_size, void* d_ws, size_t ws_size,
                              hipStream_t stream) {
  const float* x     = (const float*)d_in[0];
  const float* w_ih0 = (const float*)d_in[1];
  const float* w_hh0 = (const float*)d_in[2];
  const float* b0    = (const float*)d_in[3];
  const float* w_ih  = (const float*)d_in[4];
  const float* w_hh  = (const float*)d_in[5];
  const float* b     = (const float*)d_in[6];
  const float* w1    = (const float*)d_in[7];
  const float* b1    = (const float*)d_in[8];
  const float* w2    = (const float*)d_in[9];
  const float* b2    = (const float*)d_in[10];

  float* xp   = (float*)d_ws;                       // [2][SQ][NG] = 64MB
  float* bufA = xp + (size_t)2 * SQ * NG;           // [SQ][512]   = 16MB
  float* bufB = bufA + (size_t)SQ * 512;            // [SQ][512]   = 16MB

  const dim3 ggrid(SQ / 64, 32);

  // layer 0
  gemm_xp<<<ggrid, 256, 0, stream>>>(x, 1024, w_ih0, b0, xp);
  lstm_rec11<<<2, 512, 0, stream>>>(w_hh0, xp, bufA);

  // layers 1..4
  float* cur = bufA;
  float* nxt = bufB;
  for (int lyr = 0; lyr < 4; ++lyr) {
    gemm_xp<<<ggrid, 256, 0, stream>>>(cur, 512, w_ih + (size_t)lyr * 2 * 512 * 1024,
                                       b + (size_t)lyr * 2 * 1024, xp);
    lstm_rec11<<<2, 512, 0, stream>>>(w_hh + (size_t)lyr * 2 * 256 * 1024, xp, nxt);
    float* tmp = cur; cur = nxt; nxt = tmp;
  }

  cls_k<<<1, 512, 0, stream>>>(cur, w1, b1, w2, b2, (float*)d_out);
}